// Round 2
// baseline (580.020 us; speedup 1.0000x reference)
//
#include <hip/hip_runtime.h>
#include <hip/hip_bf16.h>

#define TT 4096      // tokens (B*S)
#define DD 768       // model dim
#define FF 3072      // ffn dim
#define EE 8         // experts
#define NSLOT 8192   // 2*TT (top-2)
#define NSLOT_PAD 8320

typedef __attribute__((ext_vector_type(8))) short bf16x8;
typedef __attribute__((ext_vector_type(4))) float f32x4;
typedef const __attribute__((address_space(1))) void* gas1_t;
typedef __attribute__((address_space(3))) void* las3_t;

// ---------------- router: one wave per token ----------------
__global__ void router_kernel(const float* __restrict__ x, const float* __restrict__ rw,
                              int* counts, int* tokE, float* tokW) {
  int wid = threadIdx.x >> 6;
  int lane = threadIdx.x & 63;
  int t = blockIdx.x * 4 + wid;
  const float* xt = x + (size_t)t * DD;
  float acc[EE];
#pragma unroll
  for (int e = 0; e < EE; ++e) acc[e] = 0.f;
#pragma unroll
  for (int i = 0; i < DD / 64; ++i) {
    float xv = xt[i * 64 + lane];
#pragma unroll
    for (int e = 0; e < EE; ++e) acc[e] += xv * rw[e * DD + i * 64 + lane];
  }
#pragma unroll
  for (int off = 32; off > 0; off >>= 1) {
#pragma unroll
    for (int e = 0; e < EE; ++e) acc[e] += __shfl_down(acc[e], off);
  }
  if (lane == 0) {
    // top-2, ties -> lower index (matches jax.lax.top_k)
    float v0 = -1e30f; int e0 = 0;
#pragma unroll
    for (int e = 0; e < EE; ++e) { if (acc[e] > v0) { v0 = acc[e]; e0 = e; } }
    float v1 = -1e30f; int e1 = 0;
#pragma unroll
    for (int e = 0; e < EE; ++e) { if (e != e0 && acc[e] > v1) { v1 = acc[e]; e1 = e; } }
    float w1 = 1.f / (1.f + __expf(v0 - v1));  // softmax over [v0, v1]
    float w0 = 1.f - w1;
    tokE[2 * t] = e0; tokE[2 * t + 1] = e1;
    tokW[2 * t] = w0; tokW[2 * t + 1] = w1;
    atomicAdd(&counts[e0], 1);
    atomicAdd(&counts[e1], 1);
  }
}

// prefix offsets + compact tile tables for both gemms
__global__ void offsets_kernel(const int* counts, int* offs, int* cursor,
                               int* tile1, int* tile2, int* meta) {
  if (threadIdx.x == 0) {
    int a = 0;
    for (int e = 0; e < EE; ++e) { offs[e] = a; cursor[e] = a; a += counts[e]; }
    offs[EE] = a;
    int n1 = 0, n2 = 0;
    for (int e = 0; e < EE; ++e) {
      int ne = counts[e];
      for (int m = 0; m < ne; m += 128) tile1[n1++] = (e << 20) | m;
      for (int m = 0; m < ne; m += 64)  tile2[n2++] = (e << 20) | m;
    }
    meta[0] = n1; meta[1] = n2;
  }
}

// fused scatter + gather: one block per token; row read once, written to both slots
__global__ void scatter_gather_kernel(const float* __restrict__ x,
                                      const int* __restrict__ tokE, const float* __restrict__ tokW,
                                      int* cursor, int* slotIdx, float* slotW,
                                      __hip_bfloat16* __restrict__ Xg) {
  int t = blockIdx.x;
  __shared__ int s01[2];
  if (threadIdx.x == 0) {
    int e0 = tokE[2 * t], e1 = tokE[2 * t + 1];
    int s0 = atomicAdd(&cursor[e0], 1);
    int s1 = atomicAdd(&cursor[e1], 1);
    slotIdx[2 * t] = s0; slotIdx[2 * t + 1] = s1;
    slotW[s0] = tokW[2 * t]; slotW[s1] = tokW[2 * t + 1];
    s01[0] = s0; s01[1] = s1;
  }
  __syncthreads();
  int s0 = s01[0], s1 = s01[1];
  const float4* src = (const float4*)(x + (size_t)t * DD);
  float4 v = src[threadIdx.x];            // 192 threads * 4 = 768
  union { ushort4 u; __hip_bfloat16 h[4]; } cv;
  cv.h[0] = __float2bfloat16(v.x);
  cv.h[1] = __float2bfloat16(v.y);
  cv.h[2] = __float2bfloat16(v.z);
  cv.h[3] = __float2bfloat16(v.w);
  ((ushort4*)(Xg + (size_t)s0 * DD))[threadIdx.x] = cv.u;
  ((ushort4*)(Xg + (size_t)s1 * DD))[threadIdx.x] = cv.u;
}

// fused transpose-convert for both weight tensors: [K][N] fp32 -> [N][K] bf16
__global__ void transpose_convert_kernel(const float* __restrict__ w_fc, __hip_bfloat16* __restrict__ wfcT,
                                         const float* __restrict__ w_proj, __hip_bfloat16* __restrict__ wprojT) {
  __shared__ float tile[64][65];
  int bx = blockIdx.x;
  const float* S; __hip_bfloat16* D; int K, N, n0, k0;
  if (bx < 576) { S = w_fc;   D = wfcT;   K = DD; N = FF; n0 = (bx % 48) * 64; k0 = (bx / 48) * 64; }
  else { bx -= 576; S = w_proj; D = wprojT; K = FF; N = DD; n0 = (bx % 12) * 64; k0 = (bx / 12) * 64; }
  S += (size_t)blockIdx.z * K * N;
  D += (size_t)blockIdx.z * K * N;
  int tid = threadIdx.x;
#pragma unroll
  for (int i = 0; i < 4; ++i) {
    int slot = i * 256 + tid;
    int r = slot >> 4, c4 = slot & 15;
    float4 v = *(const float4*)&S[(size_t)(k0 + r) * N + n0 + c4 * 4];
    tile[r][c4 * 4 + 0] = v.x; tile[r][c4 * 4 + 1] = v.y;
    tile[r][c4 * 4 + 2] = v.z; tile[r][c4 * 4 + 3] = v.w;
  }
  __syncthreads();
#pragma unroll
  for (int i = 0; i < 4; ++i) {
    int slot = i * 256 + tid;
    int n = slot >> 4, kc = slot & 15;
    union { ushort4 u; __hip_bfloat16 h[4]; } cv;
    cv.h[0] = __float2bfloat16(tile[kc * 4 + 0][n]);
    cv.h[1] = __float2bfloat16(tile[kc * 4 + 1][n]);
    cv.h[2] = __float2bfloat16(tile[kc * 4 + 2][n]);
    cv.h[3] = __float2bfloat16(tile[kc * 4 + 3][n]);
    *(ushort4*)&D[(size_t)(n0 + n) * K + k0 + kc * 4] = cv.u;
  }
}

// stage ROWS x 64-col bf16 tile global->LDS via global_load_lds width 16,
// XOR-16B swizzle (chunk s = c ^ (row&7)) to keep ds_read bank aliasing <=2-way.
template <int ROWS>
__device__ __forceinline__ void stage_tile(const short* gsrc, int ldk, short* lds, int tid) {
#pragma unroll
  for (int it = 0; it < ROWS / 32; ++it) {
    int fs = tid + it * 256;          // 16B-slot index
    int m = fs >> 3;                  // row
    int c = (fs & 7) ^ (m & 7);       // swizzled 16B column chunk
    __builtin_amdgcn_global_load_lds((gas1_t)(gsrc + (size_t)m * ldk + c * 8),
                                     (las3_t)(lds + fs * 8), 16, 0, 0);
  }
}

// fast exact-gelu via A&S 7.1.26 erf (max abs err 1.5e-7)
__device__ __forceinline__ float gelu_f(float v) {
  float z = v * 0.70710678118654752f;
  float az = fabsf(z);
  float t = 1.0f / (1.0f + 0.3275911f * az);
  float poly = t * (0.254829592f + t * (-0.284496736f + t * (1.421413741f +
               t * (-1.453152027f + t * 1.061405429f))));
  float erf_abs = 1.0f - poly * __expf(-az * az);
  float erf = copysignf(erf_abs, z);
  return 0.5f * v * (1.0f + erf);
}

// GEMM1: H[slot][FF] = gelu(Xg[slot][DD] @ wfcT + b_fc); 128x128 tiles, compact grid
__global__ __launch_bounds__(256) void gemm1_kernel(const __hip_bfloat16* __restrict__ Xg,
    const __hip_bfloat16* __restrict__ wfcT, const float* __restrict__ b_fc,
    __hip_bfloat16* __restrict__ H, const int* __restrict__ offs,
    const int* __restrict__ tile1, const int* __restrict__ meta) {
  __shared__ __align__(16) short As[128 * 64];
  __shared__ __align__(16) short Bs[128 * 64];
  if ((int)blockIdx.y >= meta[0]) return;
  int tv = tile1[blockIdx.y];
  int e = tv >> 20;
  int m_base = tv & 0xFFFFF;
  int off_e = offs[e];
  int n_e = offs[e + 1] - off_e;
  int n0 = blockIdx.x * 128;
  const short* A = (const short*)Xg + (size_t)(off_e + m_base) * DD;
  const short* B = (const short*)wfcT + (size_t)e * FF * DD + (size_t)n0 * DD;
  int tid = threadIdx.x;
  int lane = tid & 63, wid = tid >> 6;
  int l15 = lane & 15, q = lane >> 4;
  int wm = wid & 1, wn = wid >> 1;
  f32x4 acc[4][4] = {};
  for (int kk = 0; kk < DD; kk += 64) {
    stage_tile<128>(A + kk, DD, As, tid);
    stage_tile<128>(B + kk, DD, Bs, tid);
    __builtin_amdgcn_s_waitcnt(0);
    __syncthreads();
#pragma unroll
    for (int ks = 0; ks < 2; ++ks) {
      bf16x8 af[4], bfr[4];
#pragma unroll
      for (int mi = 0; mi < 4; ++mi) {
        int m = wm * 64 + mi * 16 + l15;
        int s = ((ks << 2) + q) ^ (m & 7);
        af[mi] = *(const bf16x8*)&As[m * 64 + s * 8];
      }
#pragma unroll
      for (int ni = 0; ni < 4; ++ni) {
        int n = wn * 64 + ni * 16 + l15;
        int s = ((ks << 2) + q) ^ (n & 7);
        bfr[ni] = *(const bf16x8*)&Bs[n * 64 + s * 8];
      }
#pragma unroll
      for (int mi = 0; mi < 4; ++mi)
#pragma unroll
        for (int ni = 0; ni < 4; ++ni)
          acc[mi][ni] = __builtin_amdgcn_mfma_f32_16x16x32_bf16(af[mi], bfr[ni], acc[mi][ni], 0, 0, 0);
    }
    __syncthreads();
  }
  __hip_bfloat16* Hp = H + (size_t)(off_e + m_base) * FF + n0;
#pragma unroll
  for (int mi = 0; mi < 4; ++mi) {
#pragma unroll
    for (int r = 0; r < 4; ++r) {
      int ml = wm * 64 + mi * 16 + q * 4 + r;
      if (m_base + ml < n_e) {
#pragma unroll
        for (int ni = 0; ni < 4; ++ni) {
          int nl = wn * 64 + ni * 16 + l15;
          float v = acc[mi][ni][r] + b_fc[e * FF + n0 + nl];
          Hp[(size_t)ml * FF + nl] = __float2bfloat16(gelu_f(v));
        }
      }
    }
  }
}

// GEMM2: Yw[slot][DD] = w(slot) * (H[slot][FF] @ wprojT + b_proj); 64x128 tiles
__global__ __launch_bounds__(256) void gemm2_kernel(const __hip_bfloat16* __restrict__ H,
    const __hip_bfloat16* __restrict__ wprojT, const float* __restrict__ b_proj,
    const float* __restrict__ slotW, float* __restrict__ Yw, const int* __restrict__ offs,
    const int* __restrict__ tile2, const int* __restrict__ meta) {
  __shared__ __align__(16) short As[64 * 64];
  __shared__ __align__(16) short Bs[128 * 64];
  if ((int)blockIdx.y >= meta[1]) return;
  int tv = tile2[blockIdx.y];
  int e = tv >> 20;
  int m_base = tv & 0xFFFFF;
  int off_e = offs[e];
  int n_e = offs[e + 1] - off_e;
  int n0 = blockIdx.x * 128;
  const short* A = (const short*)H + (size_t)(off_e + m_base) * FF;
  const short* B = (const short*)wprojT + (size_t)e * DD * FF + (size_t)n0 * FF;
  int tid = threadIdx.x;
  int lane = tid & 63, wid = tid >> 6;
  int l15 = lane & 15, q = lane >> 4;
  int wm = wid & 1, wn = wid >> 1;
  f32x4 acc[2][4] = {};
  for (int kk = 0; kk < FF; kk += 64) {
    stage_tile<64>(A + kk, FF, As, tid);
    stage_tile<128>(B + kk, FF, Bs, tid);
    __builtin_amdgcn_s_waitcnt(0);
    __syncthreads();
#pragma unroll
    for (int ks = 0; ks < 2; ++ks) {
      bf16x8 af[2], bfr[4];
#pragma unroll
      for (int mi = 0; mi < 2; ++mi) {
        int m = wm * 32 + mi * 16 + l15;
        int s = ((ks << 2) + q) ^ (m & 7);
        af[mi] = *(const bf16x8*)&As[m * 64 + s * 8];
      }
#pragma unroll
      for (int ni = 0; ni < 4; ++ni) {
        int n = wn * 64 + ni * 16 + l15;
        int s = ((ks << 2) + q) ^ (n & 7);
        bfr[ni] = *(const bf16x8*)&Bs[n * 64 + s * 8];
      }
#pragma unroll
      for (int mi = 0; mi < 2; ++mi)
#pragma unroll
        for (int ni = 0; ni < 4; ++ni)
          acc[mi][ni] = __builtin_amdgcn_mfma_f32_16x16x32_bf16(af[mi], bfr[ni], acc[mi][ni], 0, 0, 0);
    }
    __syncthreads();
  }
  float* Yp = Yw + (size_t)(off_e + m_base) * DD + n0;
#pragma unroll
  for (int mi = 0; mi < 2; ++mi) {
#pragma unroll
    for (int r = 0; r < 4; ++r) {
      int ml = wm * 32 + mi * 16 + q * 4 + r;
      if (m_base + ml < n_e) {
        float w = slotW[off_e + m_base + ml];
#pragma unroll
        for (int ni = 0; ni < 4; ++ni) {
          int nl = wn * 64 + ni * 16 + l15;
          Yp[(size_t)ml * DD + nl] = w * (acc[mi][ni][r] + b_proj[e * DD + n0 + nl]);
        }
      }
    }
  }
}

// out[t] = Yw[slot0(t)] + Yw[slot1(t)]  (already gate-weighted)
__global__ void combine_kernel(const float* __restrict__ Yw, const int* __restrict__ slotIdx,
                               float* __restrict__ out) {
  int idx = blockIdx.x * 256 + threadIdx.x;  // TT * (DD/4) total
  int t = idx / (DD / 4);
  int g = idx - t * (DD / 4);
  int s0 = slotIdx[2 * t], s1 = slotIdx[2 * t + 1];
  const float4 a = ((const float4*)(Yw + (size_t)s0 * DD))[g];
  const float4 b = ((const float4*)(Yw + (size_t)s1 * DD))[g];
  float4 o;
  o.x = a.x + b.x; o.y = a.y + b.y; o.z = a.z + b.z; o.w = a.w + b.w;
  ((float4*)(out + (size_t)t * DD))[g] = o;
}

extern "C" void kernel_launch(void* const* d_in, const int* in_sizes, int n_in,
                              void* d_out, int out_size, void* d_ws, size_t ws_size,
                              hipStream_t stream) {
  const float* x        = (const float*)d_in[0];
  const float* router_w = (const float*)d_in[1];
  const float* w_fc     = (const float*)d_in[2];
  const float* b_fc     = (const float*)d_in[3];
  const float* w_proj   = (const float*)d_in[4];
  const float* b_proj   = (const float*)d_in[5];
  float* out = (float*)d_out;

  char* p = (char*)d_ws;
  auto alloc = [&](size_t bytes) {
    char* r = p;
    p += (bytes + 255) & ~(size_t)255;
    return r;
  };
  __hip_bfloat16* wfcT   = (__hip_bfloat16*)alloc((size_t)EE * FF * DD * 2);  // [E][F][D]
  __hip_bfloat16* wprojT = (__hip_bfloat16*)alloc((size_t)EE * DD * FF * 2);  // [E][D][F]
  __hip_bfloat16* Xg     = (__hip_bfloat16*)alloc((size_t)NSLOT_PAD * DD * 2);
  __hip_bfloat16* H      = (__hip_bfloat16*)alloc((size_t)NSLOT_PAD * FF * 2);
  float*          Yw     = (float*)alloc((size_t)NSLOT_PAD * DD * 4);
  int*   tokE    = (int*)alloc(TT * 2 * 4);
  float* tokW    = (float*)alloc(TT * 2 * 4);
  int*   slotIdx = (int*)alloc(TT * 2 * 4);
  float* slotW   = (float*)alloc(NSLOT_PAD * 4);
  int*   tile1   = (int*)alloc(128 * 4);
  int*   tile2   = (int*)alloc(256 * 4);
  int*   counts  = (int*)alloc(64);
  int*   offs    = (int*)alloc(64);
  int*   cursor  = (int*)alloc(64);
  int*   meta    = (int*)alloc(64);

  hipMemsetAsync(counts, 0, 32, stream);
  router_kernel<<<TT / 4, 256, 0, stream>>>(x, router_w, counts, tokE, tokW);
  offsets_kernel<<<1, 64, 0, stream>>>(counts, offs, cursor, tile1, tile2, meta);
  scatter_gather_kernel<<<TT, 192, 0, stream>>>(x, tokE, tokW, cursor, slotIdx, slotW, Xg);
  transpose_convert_kernel<<<dim3(1152, 1, EE), 256, 0, stream>>>(w_fc, wfcT, w_proj, wprojT);
  gemm1_kernel<<<dim3(FF / 128, 72), 256, 0, stream>>>(Xg, wfcT, b_fc, H, offs, tile1, meta);
  gemm2_kernel<<<dim3(DD / 128, 136), 256, 0, stream>>>(H, wprojT, b_proj, slotW, Yw, offs, tile2, meta);
  combine_kernel<<<TT * (DD / 4) / 256, 256, 0, stream>>>(Yw, slotIdx, out);
}

// Round 3
// 395.221 us; speedup vs baseline: 1.4676x; 1.4676x over previous
//
#include <hip/hip_runtime.h>
#include <hip/hip_bf16.h>

#define TT 4096      // tokens (B*S)
#define DD 768       // model dim
#define FF 3072      // ffn dim
#define EE 8         // experts
#define NSLOT 8192   // 2*TT (top-2)
#define NSLOT_PAD 8320

typedef __attribute__((ext_vector_type(8))) short bf16x8;
typedef __attribute__((ext_vector_type(4))) float f32x4;
typedef const __attribute__((address_space(1))) void* gas1_t;
typedef __attribute__((address_space(3))) void* las3_t;

// ---------------- router2: 256 blocks x 16 tokens; rw in LDS; no global atomics ----
// LDS rw layout: float idx = e*832 + s*52 + j, s=slice(0..15) of 48 floats (pad 52
// breaks the 48-stride bank aliasing). 16 lanes per token, float4 everywhere.
__global__ __launch_bounds__(256) void router2_kernel(const float* __restrict__ x,
    const float* __restrict__ rw, int* __restrict__ tokE, float* __restrict__ tokW,
    int* __restrict__ blkCnt) {
  __shared__ float rws[EE * 832];
  __shared__ int cnt_s[EE];
  int tid = threadIdx.x;
  if (tid < EE) cnt_s[tid] = 0;
  // stage rw: 1536 float4 chunks, coalesced
#pragma unroll
  for (int k = 0; k < 6; ++k) {
    int c = tid + k * 256;            // 0..1535
    int e = c / 192, rem = c % 192;
    int s = rem / 12, i = rem % 12;
    float4 v = *(const float4*)&rw[e * DD + s * 48 + i * 4];
    *(float4*)&rws[e * 832 + s * 52 + i * 4] = v;
  }
  __syncthreads();
  int lane = tid & 63;
  int sl = lane & 15;                  // d-slice
  int t = blockIdx.x * 16 + (tid >> 6) * 4 + (lane >> 4);
  const float4* xp = (const float4*)(x + (size_t)t * DD + sl * 48);
  float acc[EE];
#pragma unroll
  for (int e = 0; e < EE; ++e) acc[e] = 0.f;
#pragma unroll
  for (int i = 0; i < 12; ++i) {
    float4 xv = xp[i];
#pragma unroll
    for (int e = 0; e < EE; ++e) {
      float4 rv = *(const float4*)&rws[e * 832 + sl * 52 + i * 4];
      acc[e] = fmaf(xv.x, rv.x, fmaf(xv.y, rv.y, fmaf(xv.z, rv.z, fmaf(xv.w, rv.w, acc[e]))));
    }
  }
#pragma unroll
  for (int off = 8; off > 0; off >>= 1) {
#pragma unroll
    for (int e = 0; e < EE; ++e) acc[e] += __shfl_xor(acc[e], off);
  }
  if (sl == 0) {
    float v0 = -1e30f; int e0 = 0;
#pragma unroll
    for (int e = 0; e < EE; ++e) { if (acc[e] > v0) { v0 = acc[e]; e0 = e; } }
    float v1 = -1e30f; int e1 = 0;
#pragma unroll
    for (int e = 0; e < EE; ++e) { if (e != e0 && acc[e] > v1) { v1 = acc[e]; e1 = e; } }
    float w1 = 1.f / (1.f + __expf(v0 - v1));
    float w0 = 1.f - w1;
    tokE[2 * t] = e0; tokE[2 * t + 1] = e1;
    tokW[2 * t] = w0; tokW[2 * t + 1] = w1;
    atomicAdd(&cnt_s[e0], 1);
    atomicAdd(&cnt_s[e1], 1);
  }
  __syncthreads();
  if (tid < EE) blkCnt[blockIdx.x * EE + tid] = cnt_s[tid];
}

// ---------------- offsets2: 256-wide scan of blkCnt; offsets, bases, tile tables ---
__global__ __launch_bounds__(256) void offsets2_kernel(const int* __restrict__ blkCnt,
    int* __restrict__ offs, int* __restrict__ blkBase,
    int* __restrict__ tile1, int* __restrict__ tile2, int* __restrict__ meta) {
  __shared__ int wsum[4][EE];
  int tid = threadIdx.x;
  int lane = tid & 63, w = tid >> 6;
  int c[EE], s[EE];
#pragma unroll
  for (int e = 0; e < EE; ++e) { c[e] = blkCnt[tid * EE + e]; s[e] = c[e]; }
#pragma unroll
  for (int off = 1; off < 64; off <<= 1) {
#pragma unroll
    for (int e = 0; e < EE; ++e) {
      int v = __shfl_up(s[e], off);
      if (lane >= off) s[e] += v;
    }
  }
  if (lane == 63) {
#pragma unroll
    for (int e = 0; e < EE; ++e) wsum[w][e] = s[e];
  }
  __syncthreads();
#pragma unroll
  for (int e = 0; e < EE; ++e) {
    int pre = 0;
    for (int w2 = 0; w2 < w; ++w2) pre += wsum[w2][e];
    s[e] += pre;                        // inclusive scan over 256 blocks
  }
  int tot[EE];
#pragma unroll
  for (int e = 0; e < EE; ++e) tot[e] = wsum[0][e] + wsum[1][e] + wsum[2][e] + wsum[3][e];
  int offl[EE + 1];
  offl[0] = 0;
#pragma unroll
  for (int e = 0; e < EE; ++e) offl[e + 1] = offl[e] + tot[e];
#pragma unroll
  for (int e = 0; e < EE; ++e) blkBase[tid * EE + e] = offl[e] + s[e] - c[e];
  if (tid == 0) {
    for (int e = 0; e <= EE; ++e) offs[e] = offl[e];
    int n1 = 0, n2 = 0;
    for (int e = 0; e < EE; ++e) { n1 += (tot[e] + 127) / 128; n2 += (tot[e] + 63) / 64; }
    meta[0] = n1; meta[1] = n2;
  }
  if (tid < EE) {
    int p1 = 0, p2 = 0;
    for (int e = 0; e < tid; ++e) { p1 += (tot[e] + 127) / 128; p2 += (tot[e] + 63) / 64; }
    for (int m = 0; m < tot[tid]; m += 128) tile1[p1++] = (tid << 20) | m;
    for (int m = 0; m < tot[tid]; m += 64)  tile2[p2++] = (tid << 20) | m;
  }
}

// ---------------- scatter_gather2: 256 blocks x 16 tokens; LDS cursors ------------
__global__ __launch_bounds__(256) void scatter_gather2_kernel(const float* __restrict__ x,
    const int* __restrict__ tokE, const float* __restrict__ tokW,
    const int* __restrict__ blkBase, int* __restrict__ slotIdx, float* __restrict__ slotW,
    __hip_bfloat16* __restrict__ Xg) {
  __shared__ int base_s[EE], lcur[EE];
  __shared__ int sl_s[16][2];
  int tid = threadIdx.x;
  int b = blockIdx.x;
  if (tid < EE) { base_s[tid] = blkBase[b * EE + tid]; lcur[tid] = 0; }
  __syncthreads();
  if (tid < 16) {
    int t = b * 16 + tid;
    int e0 = tokE[2 * t], e1 = tokE[2 * t + 1];
    int s0 = base_s[e0] + atomicAdd(&lcur[e0], 1);
    int s1 = base_s[e1] + atomicAdd(&lcur[e1], 1);
    slotIdx[2 * t] = s0; slotIdx[2 * t + 1] = s1;
    slotW[s0] = tokW[2 * t]; slotW[s1] = tokW[2 * t + 1];
    sl_s[tid][0] = s0; sl_s[tid][1] = s1;
  }
  __syncthreads();
  int k = tid >> 4, p = tid & 15;
  int t = b * 16 + k;
  int s0 = sl_s[k][0], s1 = sl_s[k][1];
  const float4* src = (const float4*)(x + (size_t)t * DD + p * 48);
  ushort4* d0 = (ushort4*)(Xg + (size_t)s0 * DD + p * 48);
  ushort4* d1 = (ushort4*)(Xg + (size_t)s1 * DD + p * 48);
#pragma unroll
  for (int i = 0; i < 12; ++i) {
    float4 v = src[i];
    union { ushort4 u; __hip_bfloat16 h[4]; } cv;
    cv.h[0] = __float2bfloat16(v.x);
    cv.h[1] = __float2bfloat16(v.y);
    cv.h[2] = __float2bfloat16(v.z);
    cv.h[3] = __float2bfloat16(v.w);
    d0[i] = cv.u;
    d1[i] = cv.u;
  }
}

// fused transpose-convert for both weight tensors: [K][N] fp32 -> [N][K] bf16
__global__ void transpose_convert_kernel(const float* __restrict__ w_fc, __hip_bfloat16* __restrict__ wfcT,
                                         const float* __restrict__ w_proj, __hip_bfloat16* __restrict__ wprojT) {
  __shared__ float tile[64][65];
  int bx = blockIdx.x;
  const float* S; __hip_bfloat16* D; int K, N, n0, k0;
  if (bx < 576) { S = w_fc;   D = wfcT;   K = DD; N = FF; n0 = (bx % 48) * 64; k0 = (bx / 48) * 64; }
  else { bx -= 576; S = w_proj; D = wprojT; K = FF; N = DD; n0 = (bx % 12) * 64; k0 = (bx / 12) * 64; }
  S += (size_t)blockIdx.z * K * N;
  D += (size_t)blockIdx.z * K * N;
  int tid = threadIdx.x;
#pragma unroll
  for (int i = 0; i < 4; ++i) {
    int slot = i * 256 + tid;
    int r = slot >> 4, c4 = slot & 15;
    float4 v = *(const float4*)&S[(size_t)(k0 + r) * N + n0 + c4 * 4];
    tile[r][c4 * 4 + 0] = v.x; tile[r][c4 * 4 + 1] = v.y;
    tile[r][c4 * 4 + 2] = v.z; tile[r][c4 * 4 + 3] = v.w;
  }
  __syncthreads();
#pragma unroll
  for (int i = 0; i < 4; ++i) {
    int slot = i * 256 + tid;
    int n = slot >> 4, kc = slot & 15;
    union { ushort4 u; __hip_bfloat16 h[4]; } cv;
    cv.h[0] = __float2bfloat16(tile[kc * 4 + 0][n]);
    cv.h[1] = __float2bfloat16(tile[kc * 4 + 1][n]);
    cv.h[2] = __float2bfloat16(tile[kc * 4 + 2][n]);
    cv.h[3] = __float2bfloat16(tile[kc * 4 + 3][n]);
    *(ushort4*)&D[(size_t)(n0 + n) * K + k0 + kc * 4] = cv.u;
  }
}

// stage ROWS x 64-col bf16 tile global->LDS via global_load_lds width 16,
// XOR-16B swizzle (chunk s = c ^ (row&7)) to keep ds_read bank aliasing <=2-way.
template <int ROWS>
__device__ __forceinline__ void stage_tile(const short* gsrc, int ldk, short* lds, int tid) {
#pragma unroll
  for (int it = 0; it < ROWS / 32; ++it) {
    int fs = tid + it * 256;          // 16B-slot index
    int m = fs >> 3;                  // row
    int c = (fs & 7) ^ (m & 7);       // swizzled 16B column chunk
    __builtin_amdgcn_global_load_lds((gas1_t)(gsrc + (size_t)m * ldk + c * 8),
                                     (las3_t)(lds + fs * 8), 16, 0, 0);
  }
}

// fast exact-gelu via A&S 7.1.26 erf (max abs err 1.5e-7)
__device__ __forceinline__ float gelu_f(float v) {
  float z = v * 0.70710678118654752f;
  float az = fabsf(z);
  float t = 1.0f / (1.0f + 0.3275911f * az);
  float poly = t * (0.254829592f + t * (-0.284496736f + t * (1.421413741f +
               t * (-1.453152027f + t * 1.061405429f))));
  float erf_abs = 1.0f - poly * __expf(-az * az);
  float erf = copysignf(erf_abs, z);
  return 0.5f * v * (1.0f + erf);
}

// GEMM1: H[slot][FF] = gelu(Xg[slot][DD] @ wfcT + b_fc); 128x128 tiles, compact grid
__global__ __launch_bounds__(256) void gemm1_kernel(const __hip_bfloat16* __restrict__ Xg,
    const __hip_bfloat16* __restrict__ wfcT, const float* __restrict__ b_fc,
    __hip_bfloat16* __restrict__ H, const int* __restrict__ offs,
    const int* __restrict__ tile1, const int* __restrict__ meta) {
  __shared__ __align__(16) short As[128 * 64];
  __shared__ __align__(16) short Bs[128 * 64];
  if ((int)blockIdx.y >= meta[0]) return;
  int tv = tile1[blockIdx.y];
  int e = tv >> 20;
  int m_base = tv & 0xFFFFF;
  int off_e = offs[e];
  int n_e = offs[e + 1] - off_e;
  int n0 = blockIdx.x * 128;
  const short* A = (const short*)Xg + (size_t)(off_e + m_base) * DD;
  const short* B = (const short*)wfcT + (size_t)e * FF * DD + (size_t)n0 * DD;
  int tid = threadIdx.x;
  int lane = tid & 63, wid = tid >> 6;
  int l15 = lane & 15, q = lane >> 4;
  int wm = wid & 1, wn = wid >> 1;
  f32x4 acc[4][4] = {};
  for (int kk = 0; kk < DD; kk += 64) {
    stage_tile<128>(A + kk, DD, As, tid);
    stage_tile<128>(B + kk, DD, Bs, tid);
    __builtin_amdgcn_s_waitcnt(0);
    __syncthreads();
#pragma unroll
    for (int ks = 0; ks < 2; ++ks) {
      bf16x8 af[4], bfr[4];
#pragma unroll
      for (int mi = 0; mi < 4; ++mi) {
        int m = wm * 64 + mi * 16 + l15;
        int s = ((ks << 2) + q) ^ (m & 7);
        af[mi] = *(const bf16x8*)&As[m * 64 + s * 8];
      }
#pragma unroll
      for (int ni = 0; ni < 4; ++ni) {
        int n = wn * 64 + ni * 16 + l15;
        int s = ((ks << 2) + q) ^ (n & 7);
        bfr[ni] = *(const bf16x8*)&Bs[n * 64 + s * 8];
      }
#pragma unroll
      for (int mi = 0; mi < 4; ++mi)
#pragma unroll
        for (int ni = 0; ni < 4; ++ni)
          acc[mi][ni] = __builtin_amdgcn_mfma_f32_16x16x32_bf16(af[mi], bfr[ni], acc[mi][ni], 0, 0, 0);
    }
    __syncthreads();
  }
  __hip_bfloat16* Hp = H + (size_t)(off_e + m_base) * FF + n0;
#pragma unroll
  for (int mi = 0; mi < 4; ++mi) {
#pragma unroll
    for (int r = 0; r < 4; ++r) {
      int ml = wm * 64 + mi * 16 + q * 4 + r;
      if (m_base + ml < n_e) {
#pragma unroll
        for (int ni = 0; ni < 4; ++ni) {
          int nl = wn * 64 + ni * 16 + l15;
          float v = acc[mi][ni][r] + b_fc[e * FF + n0 + nl];
          Hp[(size_t)ml * FF + nl] = __float2bfloat16(gelu_f(v));
        }
      }
    }
  }
}

// GEMM2: Yw[slot][DD] = w(slot) * (H[slot][FF] @ wprojT + b_proj); 64x128 tiles
__global__ __launch_bounds__(256) void gemm2_kernel(const __hip_bfloat16* __restrict__ H,
    const __hip_bfloat16* __restrict__ wprojT, const float* __restrict__ b_proj,
    const float* __restrict__ slotW, float* __restrict__ Yw, const int* __restrict__ offs,
    const int* __restrict__ tile2, const int* __restrict__ meta) {
  __shared__ __align__(16) short As[64 * 64];
  __shared__ __align__(16) short Bs[128 * 64];
  if ((int)blockIdx.y >= meta[1]) return;
  int tv = tile2[blockIdx.y];
  int e = tv >> 20;
  int m_base = tv & 0xFFFFF;
  int off_e = offs[e];
  int n_e = offs[e + 1] - off_e;
  int n0 = blockIdx.x * 128;
  const short* A = (const short*)H + (size_t)(off_e + m_base) * FF;
  const short* B = (const short*)wprojT + (size_t)e * DD * FF + (size_t)n0 * FF;
  int tid = threadIdx.x;
  int lane = tid & 63, wid = tid >> 6;
  int l15 = lane & 15, q = lane >> 4;
  int wm = wid & 1, wn = wid >> 1;
  f32x4 acc[2][4] = {};
  for (int kk = 0; kk < FF; kk += 64) {
    stage_tile<64>(A + kk, FF, As, tid);
    stage_tile<128>(B + kk, FF, Bs, tid);
    __builtin_amdgcn_s_waitcnt(0);
    __syncthreads();
#pragma unroll
    for (int ks = 0; ks < 2; ++ks) {
      bf16x8 af[2], bfr[4];
#pragma unroll
      for (int mi = 0; mi < 2; ++mi) {
        int m = wm * 32 + mi * 16 + l15;
        int s = ((ks << 2) + q) ^ (m & 7);
        af[mi] = *(const bf16x8*)&As[m * 64 + s * 8];
      }
#pragma unroll
      for (int ni = 0; ni < 4; ++ni) {
        int n = wn * 64 + ni * 16 + l15;
        int s = ((ks << 2) + q) ^ (n & 7);
        bfr[ni] = *(const bf16x8*)&Bs[n * 64 + s * 8];
      }
#pragma unroll
      for (int mi = 0; mi < 2; ++mi)
#pragma unroll
        for (int ni = 0; ni < 4; ++ni)
          acc[mi][ni] = __builtin_amdgcn_mfma_f32_16x16x32_bf16(af[mi], bfr[ni], acc[mi][ni], 0, 0, 0);
    }
    __syncthreads();
  }
  float* Yp = Yw + (size_t)(off_e + m_base) * DD + n0;
#pragma unroll
  for (int mi = 0; mi < 2; ++mi) {
#pragma unroll
    for (int r = 0; r < 4; ++r) {
      int ml = wm * 32 + mi * 16 + q * 4 + r;
      if (m_base + ml < n_e) {
        float w = slotW[off_e + m_base + ml];
#pragma unroll
        for (int ni = 0; ni < 4; ++ni) {
          int nl = wn * 64 + ni * 16 + l15;
          Yp[(size_t)ml * DD + nl] = w * (acc[mi][ni][r] + b_proj[e * DD + n0 + nl]);
        }
      }
    }
  }
}

// out[t] = Yw[slot0(t)] + Yw[slot1(t)]  (already gate-weighted)
__global__ void combine_kernel(const float* __restrict__ Yw, const int* __restrict__ slotIdx,
                               float* __restrict__ out) {
  int idx = blockIdx.x * 256 + threadIdx.x;  // TT * (DD/4) total
  int t = idx / (DD / 4);
  int g = idx - t * (DD / 4);
  int s0 = slotIdx[2 * t], s1 = slotIdx[2 * t + 1];
  const float4 a = ((const float4*)(Yw + (size_t)s0 * DD))[g];
  const float4 b = ((const float4*)(Yw + (size_t)s1 * DD))[g];
  float4 o;
  o.x = a.x + b.x; o.y = a.y + b.y; o.z = a.z + b.z; o.w = a.w + b.w;
  ((float4*)(out + (size_t)t * DD))[g] = o;
}

extern "C" void kernel_launch(void* const* d_in, const int* in_sizes, int n_in,
                              void* d_out, int out_size, void* d_ws, size_t ws_size,
                              hipStream_t stream) {
  const float* x        = (const float*)d_in[0];
  const float* router_w = (const float*)d_in[1];
  const float* w_fc     = (const float*)d_in[2];
  const float* b_fc     = (const float*)d_in[3];
  const float* w_proj   = (const float*)d_in[4];
  const float* b_proj   = (const float*)d_in[5];
  float* out = (float*)d_out;

  char* p = (char*)d_ws;
  auto alloc = [&](size_t bytes) {
    char* r = p;
    p += (bytes + 255) & ~(size_t)255;
    return r;
  };
  __hip_bfloat16* wfcT   = (__hip_bfloat16*)alloc((size_t)EE * FF * DD * 2);  // [E][F][D]
  __hip_bfloat16* wprojT = (__hip_bfloat16*)alloc((size_t)EE * DD * FF * 2);  // [E][D][F]
  __hip_bfloat16* Xg     = (__hip_bfloat16*)alloc((size_t)NSLOT_PAD * DD * 2);
  __hip_bfloat16* H      = (__hip_bfloat16*)alloc((size_t)NSLOT_PAD * FF * 2);
  float*          Yw     = (float*)alloc((size_t)NSLOT_PAD * DD * 4);
  int*   tokE    = (int*)alloc(TT * 2 * 4);
  float* tokW    = (float*)alloc(TT * 2 * 4);
  int*   slotIdx = (int*)alloc(TT * 2 * 4);
  float* slotW   = (float*)alloc(NSLOT_PAD * 4);
  int*   blkCnt  = (int*)alloc(256 * EE * 4);
  int*   blkBase = (int*)alloc(256 * EE * 4);
  int*   tile1   = (int*)alloc(128 * 4);
  int*   tile2   = (int*)alloc(256 * 4);
  int*   offs    = (int*)alloc(64);
  int*   meta    = (int*)alloc(64);

  router2_kernel<<<256, 256, 0, stream>>>(x, router_w, tokE, tokW, blkCnt);
  offsets2_kernel<<<1, 256, 0, stream>>>(blkCnt, offs, blkBase, tile1, tile2, meta);
  scatter_gather2_kernel<<<256, 256, 0, stream>>>(x, tokE, tokW, blkBase, slotIdx, slotW, Xg);
  transpose_convert_kernel<<<dim3(1152, 1, EE), 256, 0, stream>>>(w_fc, wfcT, w_proj, wprojT);
  gemm1_kernel<<<dim3(FF / 128, 72), 256, 0, stream>>>(Xg, wfcT, b_fc, H, offs, tile1, meta);
  gemm2_kernel<<<dim3(DD / 128, 136), 256, 0, stream>>>(H, wprojT, b_proj, slotW, Yw, offs, tile2, meta);
  combine_kernel<<<TT * (DD / 4) / 256, 256, 0, stream>>>(Yw, slotIdx, out);
}